// Round 6
// baseline (763.195 us; speedup 1.0000x reference)
//
#include <hip/hip_runtime.h>
#include <hip/hip_bf16.h>

#define N_NODES 100000
#define N_EDGES 1600000
#define D 32
#define N_GRAPHS 128

#define WIN 128                                   // nodes per window
#define NWINS ((N_NODES + WIN - 1) / WIN)         // 782
#define CAP 2560                                  // bucket capacity (mean 2046, sd ~45)
#define LSTRIDE 33                                // LDS row stride: spreads ds_add banks

// ---- Window binning: one pass, block-batched coalesced bucket writes ----
// Each block: LDS histogram of its edge chunk over 782 windows, reserve a
// contiguous range per (block,window) with ONE global atomicAdd, then scatter
// packed (dst_local<<17 | src) ints. All ~16 stores per 64B bucket line come
// from one block, temporally clustered -> full-line writebacks (fixes the
// 10x write amplification that survived both locality-scheduling attempts).
__global__ void bin_kernel(const int* __restrict__ src,
                           const int* __restrict__ dst,
                           int* __restrict__ gfill,
                           int* __restrict__ ebuf) {
    __shared__ int lhist[NWINS];
    __shared__ int lbase[NWINS];
    const int tid = threadIdx.x;
    const int per = (N_EDGES + gridDim.x - 1) / gridDim.x;
    const int e0 = blockIdx.x * per;
    const int e1 = (e0 + per < N_EDGES) ? e0 + per : N_EDGES;

    for (int b = tid; b < NWINS; b += blockDim.x) lhist[b] = 0;
    __syncthreads();
    for (int e = e0 + tid; e < e1; e += blockDim.x)
        atomicAdd(&lhist[dst[e] >> 7], 1);
    __syncthreads();
    for (int b = tid; b < NWINS; b += blockDim.x) {
        int c = lhist[b];
        lbase[b] = c ? atomicAdd(&gfill[b], c) : 0;
        lhist[b] = 0;
    }
    __syncthreads();
    for (int e = e0 + tid; e < e1; e += blockDim.x) {
        int d = dst[e];
        int bn = d >> 7;
        int r = atomicAdd(&lhist[bn], 1);
        int off = lbase[bn] + r;
        if (off < CAP) ebuf[bn * CAP + off] = ((d & (WIN - 1)) << 17) | src[e];
    }
}

// ---- Fused GIN layer, window-push version ----
// One block per 128-node window. agg[128][33] in LDS, initialized with self
// features, accumulated via ds_add_f32 from gathered neighbor rows, then the
// in-register 32x32 matvec (lane = (es,fq), W fragment in VGPRs) per node.
template <bool RELU, bool POOL>
__global__ void gin_win_kernel(const float* __restrict__ x,
                               const int* __restrict__ ebuf,
                               const int* __restrict__ gfill,
                               const float* __restrict__ W,
                               const float* __restrict__ b,
                               const int* __restrict__ graph_ids,
                               float* __restrict__ out) {
    __shared__ float agg[WIN * LSTRIDE];
    const int tid = threadIdx.x;
    const int lane = tid & 63;
    const int es = lane >> 3;      // edge-slot / input-quad
    const int fq = lane & 7;       // feature-quad
    const int wv = tid >> 6;       // wave id 0..3
    const int w = blockIdx.x;
    const int n0 = w * WIN;
    const int nloc = (N_NODES - n0 < WIN) ? (N_NODES - n0) : WIN;

    // W fragment: lane (es,fq) holds W[es*4+k][fq*4+c]
    float wf[4][4];
#pragma unroll
    for (int k = 0; k < 4; ++k) {
        const float4 t = *reinterpret_cast<const float4*>(&W[(es * 4 + k) * D + fq * 4]);
        wf[k][0] = t.x; wf[k][1] = t.y; wf[k][2] = t.z; wf[k][3] = t.w;
    }
    const float4 bv = *reinterpret_cast<const float4*>(&b[fq * 4]);

    // init agg with self features (eps=0 self term), coalesced global read
    for (int i = tid; i < nloc * D; i += blockDim.x) {
        int n = i >> 5, f = i & 31;
        agg[n * LSTRIDE + f] = x[(size_t)n0 * D + i];
    }
    __syncthreads();

    // push-accumulate neighbors: 4-deep unroll = 32 gather lines in flight/wave
    int cnt = gfill[w]; if (cnt > CAP) cnt = CAP;
    const int base = w * CAP;
    const int q0 = base + (cnt * wv) / 4;
    const int q1 = base + (cnt * (wv + 1)) / 4;
    int e = q0 + es;
    for (; e + 24 < q1; e += 32) {
        const int p0 = ebuf[e], p1 = ebuf[e + 8], p2 = ebuf[e + 16], p3 = ebuf[e + 24];
        const float4 g0 = *reinterpret_cast<const float4*>(&x[(p0 & 0x1FFFF) * D + fq * 4]);
        const float4 g1 = *reinterpret_cast<const float4*>(&x[(p1 & 0x1FFFF) * D + fq * 4]);
        const float4 g2 = *reinterpret_cast<const float4*>(&x[(p2 & 0x1FFFF) * D + fq * 4]);
        const float4 g3 = *reinterpret_cast<const float4*>(&x[(p3 & 0x1FFFF) * D + fq * 4]);
        float* a0 = &agg[(p0 >> 17) * LSTRIDE + fq * 4];
        float* a1 = &agg[(p1 >> 17) * LSTRIDE + fq * 4];
        float* a2 = &agg[(p2 >> 17) * LSTRIDE + fq * 4];
        float* a3 = &agg[(p3 >> 17) * LSTRIDE + fq * 4];
        atomicAdd(a0 + 0, g0.x); atomicAdd(a0 + 1, g0.y); atomicAdd(a0 + 2, g0.z); atomicAdd(a0 + 3, g0.w);
        atomicAdd(a1 + 0, g1.x); atomicAdd(a1 + 1, g1.y); atomicAdd(a1 + 2, g1.z); atomicAdd(a1 + 3, g1.w);
        atomicAdd(a2 + 0, g2.x); atomicAdd(a2 + 1, g2.y); atomicAdd(a2 + 2, g2.z); atomicAdd(a2 + 3, g2.w);
        atomicAdd(a3 + 0, g3.x); atomicAdd(a3 + 1, g3.y); atomicAdd(a3 + 2, g3.z); atomicAdd(a3 + 3, g3.w);
    }
    for (; e < q1; e += 8) {
        const int p0 = ebuf[e];
        const float4 g0 = *reinterpret_cast<const float4*>(&x[(p0 & 0x1FFFF) * D + fq * 4]);
        float* a0 = &agg[(p0 >> 17) * LSTRIDE + fq * 4];
        atomicAdd(a0 + 0, g0.x); atomicAdd(a0 + 1, g0.y); atomicAdd(a0 + 2, g0.z); atomicAdd(a0 + 3, g0.w);
    }
    __syncthreads();

    // matvec: wave wv handles nodes [wv*32, wv*32+32)
    float p0 = 0.f, p1 = 0.f, p2 = 0.f, p3 = 0.f;
    int gi0 = n0 + wv * 32; if (gi0 >= N_NODES) gi0 = N_NODES - 1;
    int cur_g = POOL ? graph_ids[gi0] : 0;
    for (int i = 0; i < 32; ++i) {
        const int n = wv * 32 + i;
        if (n >= nloc) break;
        const float* a = &agg[n * LSTRIDE + es * 4];
        const float q0v = a[0], q1v = a[1], q2v = a[2], q3v = a[3];
        float y0 = q0v * wf[0][0] + q1v * wf[1][0] + q2v * wf[2][0] + q3v * wf[3][0];
        float y1 = q0v * wf[0][1] + q1v * wf[1][1] + q2v * wf[2][1] + q3v * wf[3][1];
        float y2 = q0v * wf[0][2] + q1v * wf[1][2] + q2v * wf[2][2] + q3v * wf[3][2];
        float y3 = q0v * wf[0][3] + q1v * wf[1][3] + q2v * wf[2][3] + q3v * wf[3][3];
        y0 += __shfl_xor(y0, 8);  y1 += __shfl_xor(y1, 8);  y2 += __shfl_xor(y2, 8);  y3 += __shfl_xor(y3, 8);
        y0 += __shfl_xor(y0, 16); y1 += __shfl_xor(y1, 16); y2 += __shfl_xor(y2, 16); y3 += __shfl_xor(y3, 16);
        y0 += __shfl_xor(y0, 32); y1 += __shfl_xor(y1, 32); y2 += __shfl_xor(y2, 32); y3 += __shfl_xor(y3, 32);
        y0 += bv.x; y1 += bv.y; y2 += bv.z; y3 += bv.w;
        if (RELU) {
            y0 = fmaxf(y0, 0.f); y1 = fmaxf(y1, 0.f); y2 = fmaxf(y2, 0.f); y3 = fmaxf(y3, 0.f);
        }
        if (POOL) {
            const int g = graph_ids[n0 + n];
            if (g != cur_g) {
                if (es == 0) {
                    atomicAdd(&out[cur_g * D + fq * 4 + 0], p0);
                    atomicAdd(&out[cur_g * D + fq * 4 + 1], p1);
                    atomicAdd(&out[cur_g * D + fq * 4 + 2], p2);
                    atomicAdd(&out[cur_g * D + fq * 4 + 3], p3);
                }
                p0 = p1 = p2 = p3 = 0.f;
                cur_g = g;
            }
            p0 += y0; p1 += y1; p2 += y2; p3 += y3;
        } else if (es == 0) {
            float4 o; o.x = y0; o.y = y1; o.z = y2; o.w = y3;
            *reinterpret_cast<float4*>(&out[(size_t)(n0 + n) * D + fq * 4]) = o;
        }
    }
    if (POOL && es == 0) {
        atomicAdd(&out[cur_g * D + fq * 4 + 0], p0);
        atomicAdd(&out[cur_g * D + fq * 4 + 1], p1);
        atomicAdd(&out[cur_g * D + fq * 4 + 2], p2);
        atomicAdd(&out[cur_g * D + fq * 4 + 3], p3);
    }
}

extern "C" void kernel_launch(void* const* d_in, const int* in_sizes, int n_in,
                              void* d_out, int out_size, void* d_ws, size_t ws_size,
                              hipStream_t stream) {
    const float* feats = (const float*)d_in[0];
    const int* src = (const int*)d_in[1];
    const int* dst = (const int*)d_in[2];
    const int* graph_ids = (const int*)d_in[3];
    const float* W1 = (const float*)d_in[4];
    const float* b1 = (const float*)d_in[5];
    const float* W2 = (const float*)d_in[6];
    const float* b2 = (const float*)d_in[7];
    float* out = (float*)d_out;

    int* gfill  = (int*)d_ws;                       // NWINS (padded to 1024)
    int* ebuf   = gfill + 1024;                     // NWINS * CAP ints (~8 MB)
    float* h    = (float*)(ebuf + (size_t)NWINS * CAP);   // N_NODES * D floats

    // ---- Bin edges by 128-node dst window (coalesced bucket writes) ----
    hipMemsetAsync(gfill, 0, 1024 * sizeof(int), stream);
    bin_kernel<<<128, 512, 0, stream>>>(src, dst, gfill, ebuf);

    // ---- Layer 1: h = relu((x + agg(x)) @ W1 + b1) ----
    gin_win_kernel<true, false><<<NWINS, 256, 0, stream>>>(
        feats, ebuf, gfill, W1, b1, graph_ids, h);

    // ---- Layer 2 + sum pooling ----
    hipMemsetAsync(out, 0, (size_t)out_size * sizeof(float), stream);
    gin_win_kernel<false, true><<<NWINS, 256, 0, stream>>>(
        h, ebuf, gfill, W2, b2, graph_ids, out);
}

// Round 7
// 144.446 us; speedup vs baseline: 5.2836x; 5.2836x over previous
//
#include <hip/hip_runtime.h>
#include <hip/hip_bf16.h>

#define N_NODES 100000
#define N_EDGES 1600000
#define D 32
#define N_GRAPHS 128

#define WIN 128                                   // nodes per dst window
#define NWINS ((N_NODES + WIN - 1) / WIN)         // 782
#define CAP 2560                                  // bucket capacity (mean 2046)
#define NODES_PER_WAVE 8

// ---- Stage 1: bin edges by 128-node dst window, coalesced bucket writes ----
// Each block: LDS histogram of its edge chunk over the 782 windows, reserve a
// contiguous range per (block,window) with ONE global atomicAdd, then scatter
// packed (dst_local<<17 | src). Stores to a bucket arrive as contiguous runs
// from one block -> full-line writebacks (vs 10-14x amplification of the
// random-4B-store reorder, which resisted all placement-based fixes).
__global__ void bin_kernel(const int* __restrict__ src,
                           const int* __restrict__ dst,
                           int* __restrict__ gfill,
                           int* __restrict__ ebuf) {
    __shared__ int lhist[NWINS];
    __shared__ int lbase[NWINS];
    const int tid = threadIdx.x;
    const int per = (N_EDGES + gridDim.x - 1) / gridDim.x;
    const int e0 = blockIdx.x * per;
    const int e1 = (e0 + per < N_EDGES) ? e0 + per : N_EDGES;

    for (int b = tid; b < NWINS; b += blockDim.x) lhist[b] = 0;
    __syncthreads();
    for (int e = e0 + tid; e < e1; e += blockDim.x)
        atomicAdd(&lhist[dst[e] >> 7], 1);
    __syncthreads();
    for (int b = tid; b < NWINS; b += blockDim.x) {
        int c = lhist[b];
        lbase[b] = c ? atomicAdd(&gfill[b], c) : 0;
        lhist[b] = 0;
    }
    __syncthreads();
    for (int e = e0 + tid; e < e1; e += blockDim.x) {
        int d = dst[e];
        int bn = d >> 7;
        int r = atomicAdd(&lhist[bn], 1);
        int off = lbase[bn] + r;
        if (off < CAP) ebuf[bn * CAP + off] = ((d & (WIN - 1)) << 17) | src[e];
    }
}

// ---- Stage 2: exclusive scan of window counts -> global window bases ----
__global__ void wscan_kernel(const int* __restrict__ gfill, int* __restrict__ wbase) {
    __shared__ int s[1024];
    const int t = threadIdx.x;
    int v = (t < NWINS) ? gfill[t] : 0;
    s[t] = v;
    __syncthreads();
    for (int off = 1; off < 1024; off <<= 1) {
        int a = (t >= off) ? s[t - off] : 0;
        __syncthreads();
        s[t] += a;
        __syncthreads();
    }
    if (t < NWINS) wbase[t] = s[t] - v;       // exclusive
    if (t == NWINS - 1) wbase[NWINS] = s[t];  // total
}

// ---- Stage 3: per-window local sort in LDS -> dst-sorted CSR, all writes
// coalesced. One block per window: bucket -> LDS, 128-bin histogram + scan,
// scatter within LDS, stream out esrc / rend / deg sequentially.
__global__ void csr_local_kernel(const int* __restrict__ ebuf,
                                 const int* __restrict__ wbase,
                                 int* __restrict__ esrc,
                                 int* __restrict__ rend,
                                 int* __restrict__ deg) {
    __shared__ int pk[CAP];
    __shared__ int ssrc[CAP];
    __shared__ int hs[WIN];
    __shared__ int hcnt[WIN];
    __shared__ int cur[WIN];
    const int tid = threadIdx.x;
    const int w = blockIdx.x;
    const int base_out = wbase[w];
    int cnt = wbase[w + 1] - base_out;
    if (cnt > CAP) cnt = CAP;
    const int n0 = w * WIN;

    for (int i = tid; i < cnt; i += 256) pk[i] = ebuf[w * CAP + i];
    if (tid < WIN) hcnt[tid] = 0;
    __syncthreads();
    for (int i = tid; i < cnt; i += 256) atomicAdd(&hcnt[pk[i] >> 17], 1);
    __syncthreads();
    if (tid < WIN) hs[tid] = hcnt[tid];
    __syncthreads();
    for (int off = 1; off < WIN; off <<= 1) {
        int a = 0;
        if (tid < WIN && tid >= off) a = hs[tid - off];
        __syncthreads();
        if (tid < WIN) hs[tid] += a;
        __syncthreads();
    }
    if (tid < WIN) {
        const int incl = hs[tid];
        const int c = hcnt[tid];
        cur[tid] = incl - c;
        const int n = n0 + tid;
        if (n < N_NODES) { rend[n] = base_out + incl; deg[n] = c; }
    }
    __syncthreads();
    for (int i = tid; i < cnt; i += 256) {
        const int p = pk[i];
        const int pos = atomicAdd(&cur[p >> 17], 1);
        ssrc[pos] = p & 0x1FFFF;
    }
    __syncthreads();
    for (int i = tid; i < cnt; i += 256) esrc[base_out + i] = ssrc[i];
}

// ---- Fused GIN layer (pull mode, proven in rounds 3-5) ----
// Wave = 8 edge-slots (es) x 8 feature-quads (fq); one gather instruction
// covers 8 edges x 128B. W fragment in registers. Wave owns 8 contiguous
// nodes; POOL accumulates per-graph in registers (graph_ids sorted).
template <bool RELU, bool POOL>
__global__ void gin_layer_kernel(const float* __restrict__ x,
                                 const int* __restrict__ esrc,
                                 const int* __restrict__ rend,
                                 const int* __restrict__ deg,
                                 const float* __restrict__ W,
                                 const float* __restrict__ b,
                                 const int* __restrict__ graph_ids,
                                 float* __restrict__ out) {
    const int lane = threadIdx.x & 63;
    const int es = lane >> 3;
    const int fq = lane & 7;

    float w[4][4];
#pragma unroll
    for (int k = 0; k < 4; ++k) {
        const float4 wv = *reinterpret_cast<const float4*>(&W[(es * 4 + k) * D + fq * 4]);
        w[k][0] = wv.x; w[k][1] = wv.y; w[k][2] = wv.z; w[k][3] = wv.w;
    }
    const float4 bv = *reinterpret_cast<const float4*>(&b[fq * 4]);

    const int wid = blockIdx.x * (blockDim.x >> 6) + (threadIdx.x >> 6);
    const int v0 = wid * NODES_PER_WAVE;
    if (v0 >= N_NODES) return;
    const int v1 = (v0 + NODES_PER_WAVE < N_NODES) ? v0 + NODES_PER_WAVE : N_NODES;

    float p0 = 0.f, p1 = 0.f, p2 = 0.f, p3 = 0.f;
    int cur_g = POOL ? graph_ids[v0] : 0;

    for (int v = v0; v < v1; ++v) {
        const int end = rend[v];
        const int dg = deg[v];
        int e = end - dg;

        float a0, a1, a2, a3;
        if (es == 0) {   // self term (eps = 0)
            const float4 xv = *reinterpret_cast<const float4*>(&x[(size_t)v * D + fq * 4]);
            a0 = xv.x; a1 = xv.y; a2 = xv.z; a3 = xv.w;
        } else { a0 = a1 = a2 = a3 = 0.f; }

        for (; e + 16 <= end; e += 16) {
            const int s0 = esrc[e + es];
            const int s1 = esrc[e + 8 + es];
            const float4 g0 = *reinterpret_cast<const float4*>(&x[(size_t)s0 * D + fq * 4]);
            const float4 g1 = *reinterpret_cast<const float4*>(&x[(size_t)s1 * D + fq * 4]);
            a0 += g0.x; a1 += g0.y; a2 += g0.z; a3 += g0.w;
            a0 += g1.x; a1 += g1.y; a2 += g1.z; a3 += g1.w;
        }
        if (e + 8 <= end) {
            const int s0 = esrc[e + es];
            const float4 g0 = *reinterpret_cast<const float4*>(&x[(size_t)s0 * D + fq * 4]);
            a0 += g0.x; a1 += g0.y; a2 += g0.z; a3 += g0.w;
            e += 8;
        }
        const int rem = end - e;
        if (es < rem) {
            const int s0 = esrc[e + es];
            const float4 g0 = *reinterpret_cast<const float4*>(&x[(size_t)s0 * D + fq * 4]);
            a0 += g0.x; a1 += g0.y; a2 += g0.z; a3 += g0.w;
        }

        a0 += __shfl_xor(a0, 8);  a1 += __shfl_xor(a1, 8);  a2 += __shfl_xor(a2, 8);  a3 += __shfl_xor(a3, 8);
        a0 += __shfl_xor(a0, 16); a1 += __shfl_xor(a1, 16); a2 += __shfl_xor(a2, 16); a3 += __shfl_xor(a3, 16);
        a0 += __shfl_xor(a0, 32); a1 += __shfl_xor(a1, 32); a2 += __shfl_xor(a2, 32); a3 += __shfl_xor(a3, 32);

        const float q0 = __shfl(a0, es, 8);
        const float q1 = __shfl(a1, es, 8);
        const float q2 = __shfl(a2, es, 8);
        const float q3 = __shfl(a3, es, 8);

        float y0 = q0 * w[0][0] + q1 * w[1][0] + q2 * w[2][0] + q3 * w[3][0];
        float y1 = q0 * w[0][1] + q1 * w[1][1] + q2 * w[2][1] + q3 * w[3][1];
        float y2 = q0 * w[0][2] + q1 * w[1][2] + q2 * w[2][2] + q3 * w[3][2];
        float y3 = q0 * w[0][3] + q1 * w[1][3] + q2 * w[2][3] + q3 * w[3][3];

        y0 += __shfl_xor(y0, 8);  y1 += __shfl_xor(y1, 8);  y2 += __shfl_xor(y2, 8);  y3 += __shfl_xor(y3, 8);
        y0 += __shfl_xor(y0, 16); y1 += __shfl_xor(y1, 16); y2 += __shfl_xor(y2, 16); y3 += __shfl_xor(y3, 16);
        y0 += __shfl_xor(y0, 32); y1 += __shfl_xor(y1, 32); y2 += __shfl_xor(y2, 32); y3 += __shfl_xor(y3, 32);

        y0 += bv.x; y1 += bv.y; y2 += bv.z; y3 += bv.w;
        if (RELU) {
            y0 = fmaxf(y0, 0.f); y1 = fmaxf(y1, 0.f); y2 = fmaxf(y2, 0.f); y3 = fmaxf(y3, 0.f);
        }

        if (POOL) {
            const int g = graph_ids[v];
            if (g != cur_g) {
                if (es == 0) {
                    atomicAdd(&out[cur_g * D + fq * 4 + 0], p0);
                    atomicAdd(&out[cur_g * D + fq * 4 + 1], p1);
                    atomicAdd(&out[cur_g * D + fq * 4 + 2], p2);
                    atomicAdd(&out[cur_g * D + fq * 4 + 3], p3);
                }
                p0 = p1 = p2 = p3 = 0.f;
                cur_g = g;
            }
            p0 += y0; p1 += y1; p2 += y2; p3 += y3;
        } else {
            if (es == 0) {
                float4 o; o.x = y0; o.y = y1; o.z = y2; o.w = y3;
                *reinterpret_cast<float4*>(&out[(size_t)v * D + fq * 4]) = o;
            }
        }
    }
    if (POOL && es == 0) {
        atomicAdd(&out[cur_g * D + fq * 4 + 0], p0);
        atomicAdd(&out[cur_g * D + fq * 4 + 1], p1);
        atomicAdd(&out[cur_g * D + fq * 4 + 2], p2);
        atomicAdd(&out[cur_g * D + fq * 4 + 3], p3);
    }
}

extern "C" void kernel_launch(void* const* d_in, const int* in_sizes, int n_in,
                              void* d_out, int out_size, void* d_ws, size_t ws_size,
                              hipStream_t stream) {
    const float* feats = (const float*)d_in[0];
    const int* src = (const int*)d_in[1];
    const int* dst = (const int*)d_in[2];
    const int* graph_ids = (const int*)d_in[3];
    const float* W1 = (const float*)d_in[4];
    const float* b1 = (const float*)d_in[5];
    const float* W2 = (const float*)d_in[6];
    const float* b2 = (const float*)d_in[7];
    float* out = (float*)d_out;

    int* gfill = (int*)d_ws;                               // 1024
    int* wbase = gfill + 1024;                             // 1024 (NWINS+1)
    int* ebuf  = wbase + 1024;                             // NWINS*CAP (~8 MB)
    int* esrc  = ebuf + (size_t)NWINS * CAP;               // N_EDGES
    int* rend  = esrc + N_EDGES;                           // N_NODES
    int* deg   = rend + N_NODES;                           // N_NODES
    float* h   = (float*)(deg + N_NODES);                  // N_NODES*D

    const int total_waves = (N_NODES + NODES_PER_WAVE - 1) / NODES_PER_WAVE;  // 12500
    const int layer_blocks = (total_waves + 3) / 4;

    // ---- Build dst-sorted CSR via window binning + LDS-local sort ----
    hipMemsetAsync(gfill, 0, 1024 * sizeof(int), stream);
    bin_kernel<<<256, 512, 0, stream>>>(src, dst, gfill, ebuf);
    wscan_kernel<<<1, 1024, 0, stream>>>(gfill, wbase);
    csr_local_kernel<<<NWINS, 256, 0, stream>>>(ebuf, wbase, esrc, rend, deg);

    // ---- Layer 1: h = relu((x + agg(x)) @ W1 + b1) ----
    gin_layer_kernel<true, false><<<layer_blocks, 256, 0, stream>>>(
        feats, esrc, rend, deg, W1, b1, graph_ids, h);

    // ---- Layer 2 + sum pooling ----
    hipMemsetAsync(out, 0, (size_t)out_size * sizeof(float), stream);
    gin_layer_kernel<false, true><<<layer_blocks, 256, 0, stream>>>(
        h, esrc, rend, deg, W2, b2, graph_ids, out);
}